// Round 9
// baseline (583.428 us; speedup 1.0000x reference)
//
#include <hip/hip_runtime.h>
#include <math.h>

// Problem constants (fixed by reference setup_inputs)
#define B_ 16
#define C_ 512
#define N_ 4096   // 64*64
#define K_ 64

// Workspace layout (float offsets). Total ~689K floats = 2.76 MB.
#define OFF_PBIG    0         // [16 chunk][16 kstep][2 kh][64 lane] uint4 = 512 KB
#define OFF_INVSIG  131072    // [K][C] 1/sigma fp32
#define OFF_WSUM    163840    // [B][K]
#define OFF_GSUM    164864    // [B]
#define OFF_WX      164992    // [B][K][C] fp32, atomic-accumulated by k_agg

typedef short bf16x8 __attribute__((ext_vector_type(8)));   // 8 bf16 in 4 VGPRs
typedef float f32x16 __attribute__((ext_vector_type(16)));  // MFMA 32x32 accumulator

union U4 { uint4 u; bf16x8 b; };

__device__ __forceinline__ unsigned hi16(float f) { return __float_as_uint(f) >> 16; }
__device__ __forceinline__ unsigned hi16rne(float f) {
  return (__float_as_uint(f) + 0x8000u) >> 16;
}
__device__ __forceinline__ float fromhi(unsigned h) { return __uint_as_float(h << 16); }
// pack two floats' truncated-bf16 into one dword: low16 = bf16(lo), high16 = bf16(hi)
__device__ __forceinline__ unsigned pk(float lo, float hi) {
  return (__float_as_uint(lo) >> 16) | (__float_as_uint(hi) & 0xFFFF0000u);
}

// ---------------------------------------------------------------- kernel 1
// Build pbig (MFMA-fragment order), invsig; zero wsum/gsum/wx. One block per k.
// pbig uint4 index for (k,c): chunk=c>>5, ks=(c&31)>>1, lh=c&1, kh=k>>5:
//   (((chunk*16+ks)*2+kh)*64 + lh*32 + (k&31))
__global__ void k_prep(const float* __restrict__ anchor,
                       const float* __restrict__ sraw,
                       unsigned* __restrict__ pbig,
                       float* __restrict__ invsig,
                       float* __restrict__ wsum,
                       float* __restrict__ gsum,
                       float* __restrict__ wx) {
  const int k = blockIdx.x;
  const int t = threadIdx.x;
  __shared__ float s_is2[C_], s_m[C_];
  __shared__ float red[4];
  float part = 0.f;
#pragma unroll
  for (int r = 0; r < 2; r++) {
    int c = r * 256 + t;
    float a = anchor[k * C_ + c];
    float sg = 1.f / (1.f + __expf(-sraw[k * C_ + c]));
    float is = 1.f / sg;
    float is2 = is * is;
    s_is2[c] = is2;
    s_m[c] = -2.f * a * is2;
    invsig[k * C_ + c] = is;
    part = fmaf(a * a, is2, part);
  }
  float v = part;
#pragma unroll
  for (int off = 32; off; off >>= 1) v += __shfl_down(v, off);
  if ((t & 63) == 0) red[t >> 6] = v;
  __syncthreads();
  float cst = red[0] + red[1] + red[2] + red[3];
  unsigned ch = hi16(cst);
  unsigned clr = hi16rne(cst - fromhi(ch));
#pragma unroll
  for (int r = 0; r < 2; r++) {
    int c = r * 256 + t;
    float is2 = s_is2[c], m = s_m[c];
    unsigned ih = hi16(is2);
    unsigned ilr = hi16rne(is2 - fromhi(ih));
    unsigned mh = hi16(m);
    unsigned mlr = hi16rne(m - fromhi(mh));
    int chunk = c >> 5, ks = (c & 31) >> 1, lh = c & 1;
    int kh = k >> 5;
    size_t dst = ((((size_t)chunk * 16 + ks) * 2 + kh) * 64 + lh * 32 + (k & 31)) * 4;
    pbig[dst + 0] = ih | (ilr << 16);
    pbig[dst + 1] = ih | (mh << 16);
    pbig[dst + 2] = mlr | (mh << 16);
    pbig[dst + 3] = (c == 0) ? (ch | (clr << 16)) : 0u;
  }
  // zero wx slice for this k-block: 8192 floats = 2048 float4
  float4 z4 = make_float4(0.f, 0.f, 0.f, 0.f);
  float4* wz = (float4*)(wx + (size_t)k * 8192);
#pragma unroll
  for (int it = 0; it < 8; it++) wz[it * 256 + t] = z4;
  if (k == 0) {
    for (int i = t; i < B_ * K_; i += 256) wsum[i] = 0.f;
    if (t < B_) gsum[t] = 0.f;
  }
}

// ---------------------------------------------------------------- kernel 2
// MFMA distance GEMM (split-bf16, inner dim 4096) + softmax.
// v7: split-C for TLP. Each wave: (kh, chalf) quarter -- 32 k-rows x 64 n-cols
// over HALF the C range (8 chunks). Grid 1024 x 4 waves = 4096 waves =
// 4 blocks/CU = 4 waves/SIMD (v6's grid supplied only 2/SIMD; per-chunk
// latency ~900cy > ~830cy compute window was uncoverable). Same register
// pipeline as v6 (f0_/f1_ + a/b x double-buffers, all-static).
// Epilogue: chalf-pair exchange via padded LDS (static branches, r3 pattern),
// then cross-kh softmax via cmax/csum.
__global__ __launch_bounds__(256, 4) void k_dist(
    const float* __restrict__ x,
    const unsigned* __restrict__ pbig,
    float* __restrict__ soft,
    float* __restrict__ wsum) {
  const int bid = blockIdx.x;
  const int swz = (bid & 7) * 128 + (bid >> 3);  // XCD remap (1024%8==0, bijective)
  const int b = swz >> 6;                        // 16 batches (64 blocks each)
  const int nblk = (swz & 63) * 64;              // 64 n-blocks of 64
  const int tid = threadIdx.x;
  const int wid = tid >> 6;
  const int lane = tid & 63;
  const int l31 = lane & 31;
  const int lh = lane >> 5;
  const int kh = wid & 1;                        // k-half
  const int chalf = wid >> 1;                    // C-half this wave accumulates

  __shared__ float exch[4][64][20];              // 20.5 KB, 80B/lane (16B-aligned)
  __shared__ float cmax[4][32];
  __shared__ float csum[4][32];

  f32x16 accA, accB;                             // cols nblk+0..31 / +32..63
#pragma unroll
  for (int i = 0; i < 16; i++) { accA[i] = 0.f; accB[i] = 0.f; }

  const float* xcol0 = x + (size_t)b * (C_ * N_) + nblk + l31;
  const float* xcol1 = xcol0 + 32;
  const uint4* pf = (const uint4*)pbig + (size_t)kh * 64 + lane;

#define PACKMF(XV, CC, ACC, AFRAG)                                            \
  {                                                                           \
    float xv = (XV);                                                          \
    float x2 = xv * xv;                                                       \
    unsigned u = __float_as_uint(xv);                                         \
    unsigned u2 = __float_as_uint(x2);                                        \
    unsigned uhf = u & 0xFFFF0000u;                                           \
    unsigned u2hf = u2 & 0xFFFF0000u;                                         \
    float xl = xv - __uint_as_float(uhf);                                     \
    float x2l = x2 - __uint_as_float(u2hf);                                   \
    U4 bf;                                                                    \
    bf.u.x = (u2 >> 16) | u2hf;                                               \
    bf.u.y = ((__float_as_uint(x2l) + 0x8000u) >> 16) | uhf;                  \
    bf.u.z = (u >> 16) | ((__float_as_uint(xl) + 0x8000u) & 0xFFFF0000u);     \
    bf.u.w = ((CC) == 0) ? 0x3F803F80u : 0u;                                  \
    ACC = __builtin_amdgcn_mfma_f32_32x32x16_bf16((AFRAG), bf.b, ACC, 0, 0, 0); \
  }

#define CHUNK_BODY(CHUNK, FCUR, FNXT, XC0, XC1, XN0, XN1, PREFETCH)           \
  {                                                                           \
    const int chunk_ = (CHUNK);                                               \
    if (PREFETCH) {                                                           \
      _Pragma("unroll")                                                       \
      for (int kk = 0; kk < 16; kk++) {                                       \
        FNXT[kk].u = pf[(size_t)((chunk_ + 1) * 16 + kk) * 128];              \
        XN0[kk] = xcol0[(size_t)((chunk_ + 1) * 32 + kk * 2 + lh) * N_];      \
        XN1[kk] = xcol1[(size_t)((chunk_ + 1) * 32 + kk * 2 + lh) * N_];      \
      }                                                                       \
    }                                                                         \
    _Pragma("unroll")                                                         \
    for (int ks = 0; ks < 16; ks++) {                                         \
      const int c = chunk_ * 32 + ks * 2 + lh;                                \
      PACKMF(XC0[ks], c, accA, FCUR[ks].b);                                   \
      PACKMF(XC1[ks], c, accB, FCUR[ks].b);                                   \
    }                                                                         \
  }

  U4 f0_[16], f1_[16];
  float a0_[16], a1_[16], b0_[16], b1_[16];
  const int cbase = chalf * 8;                   // this wave's 8 chunks
#pragma unroll
  for (int kk = 0; kk < 16; kk++) {
    f0_[kk].u = pf[(size_t)(cbase * 16 + kk) * 128];
    a0_[kk] = xcol0[(size_t)(cbase * 32 + kk * 2 + lh) * N_];
    a1_[kk] = xcol1[(size_t)(cbase * 32 + kk * 2 + lh) * N_];
  }
  for (int c2 = 0; c2 < 4; c2++) {
    CHUNK_BODY(cbase + 2 * c2,     f0_, f1_, a0_, a1_, b0_, b1_, 1);
    CHUNK_BODY(cbase + 2 * c2 + 1, f1_, f0_, b0_, b1_, a0_, a1_, (c2 < 3));
  }
#undef CHUNK_BODY
#undef PACKMF

  // ---- chalf-pair exchange (partner wid^2), ALL STATIC indices.
  // chalf==0 keeps accA (cols 0-31), gives accB; chalf==1 keeps accB
  // (cols 32-63), gives accA. After: own = full-C 32k x 32n tile.
  {
    float* pw = &exch[wid][lane][0];
    if (chalf == 0) {
#pragma unroll
      for (int q = 0; q < 4; q++)
        *(float4*)&pw[q * 4] = make_float4(accB[q * 4], accB[q * 4 + 1],
                                           accB[q * 4 + 2], accB[q * 4 + 3]);
    } else {
#pragma unroll
      for (int q = 0; q < 4; q++)
        *(float4*)&pw[q * 4] = make_float4(accA[q * 4], accA[q * 4 + 1],
                                           accA[q * 4 + 2], accA[q * 4 + 3]);
    }
  }
  __syncthreads();
  f32x16 own;
  {
    const float* pr = &exch[wid ^ 2][lane][0];
    if (chalf == 0) {
#pragma unroll
      for (int r = 0; r < 16; r++) own[r] = accA[r] + pr[r];
    } else {
#pragma unroll
      for (int r = 0; r < 16; r++) own[r] = accB[r] + pr[r];
    }
  }

  // ---- softmax over k=64: cross-kh partner wid^1 (same col-half). ----
  float* softb = soft + (size_t)b * (K_ * N_);
  float mm = -3.4e38f;
#pragma unroll
  for (int r = 0; r < 16; r++) {
    own[r] *= -0.5f;
    mm = fmaxf(mm, own[r]);
  }
  mm = fmaxf(mm, __shfl_xor(mm, 32));
  cmax[wid][l31] = mm;
  __syncthreads();
  float m = fmaxf(cmax[wid][l31], cmax[wid ^ 1][l31]);
  float ss = 0.f;
#pragma unroll
  for (int r = 0; r < 16; r++) {
    own[r] = __expf(own[r] - m);
    ss += own[r];
  }
  ss += __shfl_xor(ss, 32);
  csum[wid][l31] = ss;
  __syncthreads();
  float inv = 1.f / (csum[wid][l31] + csum[wid ^ 1][l31]);
  const int nc = nblk + chalf * 32 + l31;        // this wave's column
#pragma unroll
  for (int r = 0; r < 16; r++) {
    float w = own[r] * inv;
    own[r] = w;
    int k0 = kh * 32 + (r & 3) + 8 * (r >> 2) + 4 * lh;
    softb[(size_t)k0 * N_ + nc] = w;
  }
  // ---- wsum: reduce own 32 cols, one atomic per k-row (per lh half) ----
#pragma unroll
  for (int r = 0; r < 16; r++) {
    float v = own[r];
    v += __shfl_xor(v, 1);
    v += __shfl_xor(v, 2);
    v += __shfl_xor(v, 4);
    v += __shfl_xor(v, 8);
    v += __shfl_xor(v, 16);
    if (l31 == 0) {
      int k0 = kh * 32 + (r & 3) + 8 * (r >> 2) + 4 * lh;
      atomicAdd(&wsum[b * K_ + k0], v);
    }
  }
}

// ---------------------------------------------------------------- kernel 3
// Aggregation GEMM via MFMA: wx[b,k,c] += sum_n soft[b,k,n]*x[b,c,n].
// v7: n split 8 ways (z), grid 2048 = 8 blocks/CU (v6 was 4). XCD-group
// swizzle; partials atomicAdd'ed into zero-initialized wx (16 adds/element).
__global__ __launch_bounds__(256, 4) void k_agg(const float* __restrict__ x,
                                                const float* __restrict__ soft,
                                                float* __restrict__ wx) {
  const int bid = blockIdx.x;
  const int xcd = bid & 7, slot = bid >> 3;      // 256 slots per XCD
  const int grp = (slot >> 4) * 8 + xcd;         // 0..127 = (b,z) group
  const int ct = slot & 15;
  const int b = grp & 15, z = grp >> 4;          // z 0..7
  const int tid = threadIdx.x;
  const int wid = tid >> 6, lane = tid & 63, l31 = lane & 31, lh = lane >> 5;
  const int c0 = ct * 32;
  const int n0 = z * 512 + wid * 128;
  __shared__ float red[4][64][36];  // stride 36 floats (odd x16B) per lane

  f32x16 acc[2];
#pragma unroll
  for (int kt = 0; kt < 2; kt++)
#pragma unroll
    for (int i = 0; i < 16; i++) acc[kt][i] = 0.f;

  const float* sb = soft + (size_t)b * (K_ * N_);
  const float* xr = x + (size_t)b * (C_ * N_) + (size_t)(c0 + l31) * N_;
  const float* s0 = sb + (size_t)l31 * N_;
  const float* s1 = sb + (size_t)(32 + l31) * N_;

#pragma unroll 2
  for (int kstep = 0; kstep < 8; kstep++) {
    int nb = n0 + kstep * 16 + lh * 8;
    float4 f0 = *(const float4*)&s0[nb];
    float4 f1 = *(const float4*)&s0[nb + 4];
    float4 g0 = *(const float4*)&s1[nb];
    float4 g1 = *(const float4*)&s1[nb + 4];
    float4 h0 = *(const float4*)&xr[nb];
    float4 h1 = *(const float4*)&xr[nb + 4];
    U4 A0, A1, Bf;
    A0.u.x = pk(f0.x, f0.y); A0.u.y = pk(f0.z, f0.w);
    A0.u.z = pk(f1.x, f1.y); A0.u.w = pk(f1.z, f1.w);
    A1.u.x = pk(g0.x, g0.y); A1.u.y = pk(g0.z, g0.w);
    A1.u.z = pk(g1.x, g1.y); A1.u.w = pk(g1.z, g1.w);
    Bf.u.x = pk(h0.x, h0.y); Bf.u.y = pk(h0.z, h0.w);
    Bf.u.z = pk(h1.x, h1.y); Bf.u.w = pk(h1.z, h1.w);
    acc[0] = __builtin_amdgcn_mfma_f32_32x32x16_bf16(A0.b, Bf.b, acc[0], 0, 0, 0);
    acc[1] = __builtin_amdgcn_mfma_f32_32x32x16_bf16(A1.b, Bf.b, acc[1], 0, 0, 0);
  }
  // stash per-wave partials
#pragma unroll
  for (int kt = 0; kt < 2; kt++)
#pragma unroll
    for (int q = 0; q < 4; q++) {
      float4 vv = make_float4(acc[kt][q * 4], acc[kt][q * 4 + 1],
                              acc[kt][q * 4 + 2], acc[kt][q * 4 + 3]);
      *(float4*)&red[wid][lane][kt * 16 + q * 4] = vv;
    }
  __syncthreads();
  // cross-wave reduce + atomic accumulate (2048 outputs, 8 per thread)
  const int lt = tid & 63, sb4 = (tid >> 6) * 8;
  float v[8];
#pragma unroll
  for (int i = 0; i < 8; i++) v[i] = 0.f;
#pragma unroll
  for (int w = 0; w < 4; w++)
#pragma unroll
    for (int i = 0; i < 8; i++) v[i] += red[w][lt][sb4 + i];
#pragma unroll
  for (int i = 0; i < 8; i++) {
    int s = sb4 + i;
    int kt = s >> 4, r = s & 15;
    int k = kt * 32 + (r & 3) + 8 * (r >> 2) + 4 * (lt >> 5);
    atomicAdd(&wx[((size_t)b * K_ + k) * C_ + c0 + (lt & 31)], v[i]);
  }
}

// ---------------------------------------------------------------- kernel 4
// nodes = (wx - wsum*anchor)/sigma/(wsum+eps); intra L2-norm -> out0; gsum.
__global__ void k_nodes(const float* __restrict__ wx,
                        const float* __restrict__ wsum,
                        const float* __restrict__ anchor,
                        const float* __restrict__ invsig,
                        float* __restrict__ out0,
                        float* __restrict__ gsum) {
  const int k = blockIdx.x, b = blockIdx.y;
  const int tid = threadIdx.x;
  float wsv = wsum[b * K_ + k];
  float winv = 1.f / (wsv + 1e-9f);
  float vals[4];
  float local = 0.f;
#pragma unroll
  for (int r = 0; r < 4; r++) {
    int c = r * 128 + tid;
    float w = wx[((size_t)b * K_ + k) * C_ + c];
    float v = (w - wsv * anchor[k * C_ + c]) * invsig[k * C_ + c] * winv;
    vals[r] = v;
    local = fmaf(v, v, local);
  }
  float v = local;
#pragma unroll
  for (int off = 32; off; off >>= 1) v += __shfl_down(v, off);
  __shared__ float red[2];
  if ((tid & 63) == 0) red[tid >> 6] = v;
  __syncthreads();
  float sumsq = red[0] + red[1];
  float norm = sqrtf(sumsq);
  float scale = 1.f / fmaxf(norm, 1e-12f);
#pragma unroll
  for (int r = 0; r < 4; r++) {
    int c = r * 128 + tid;
    out0[((size_t)b * K_ + k) * C_ + c] = vals[r] * scale;
  }
  if (tid == 0) atomicAdd(&gsum[b], sumsq * scale * scale);
}

// ---------------------------------------------------------------- kernel 5
// Global L2 scale in place on out0 ([B][K*C] flat == reference (B,C,K)).
__global__ void k_final(float* __restrict__ out0,
                        const float* __restrict__ gsum) {
  for (int i = blockIdx.x * 256 + threadIdx.x; i < B_ * K_ * C_;
       i += gridDim.x * 256) {
    int b = i >> 15;  // K_*C_ = 32768
    out0[i] = out0[i] * (1.f / fmaxf(sqrtf(gsum[b]), 1e-12f));
  }
}

// ---------------------------------------------------------------- launch
extern "C" void kernel_launch(void* const* d_in, const int* in_sizes, int n_in,
                              void* d_out, int out_size, void* d_ws, size_t ws_size,
                              hipStream_t stream) {
  const float* x = (const float*)d_in[0];       // [B,C,H,W]
  const float* anchor = (const float*)d_in[1];  // [K,C]
  const float* sraw = (const float*)d_in[2];    // [K,C]
  float* out0 = (float*)d_out;                          // [B,C,K] flat
  float* soft = out0 + (size_t)B_ * C_ * K_;            // [B,K,N] (output 1)
  float* ws = (float*)d_ws;

  unsigned* pbig = (unsigned*)(ws + OFF_PBIG);
  float* invsig = ws + OFF_INVSIG;
  float* wsum = ws + OFF_WSUM;
  float* gsum = ws + OFF_GSUM;
  float* wx = ws + OFF_WX;

  k_prep<<<K_, 256, 0, stream>>>(anchor, sraw, pbig, invsig, wsum, gsum, wx);
  k_dist<<<1024, 256, 0, stream>>>(x, pbig, soft, wsum);
  k_agg<<<2048, 256, 0, stream>>>(x, soft, wx);
  k_nodes<<<dim3(K_, B_), 128, 0, stream>>>(wx, wsum, anchor, invsig, out0,
                                            gsum);
  k_final<<<512, 256, 0, stream>>>(out0, gsum);
}

// Round 10
// 453.316 us; speedup vs baseline: 1.2870x; 1.2870x over previous
//
#include <hip/hip_runtime.h>
#include <math.h>

// Problem constants (fixed by reference setup_inputs)
#define B_ 16
#define C_ 512
#define N_ 4096   // 64*64
#define K_ 64

// Workspace layout (float offsets). Total ~689K floats = 2.76 MB.
#define OFF_PBIG    0         // [16 chunk][16 kstep][2 kh][64 lane] uint4 = 512 KB
#define OFF_INVSIG  131072    // [K][C] 1/sigma fp32
#define OFF_WSUM    163840    // [B][K]
#define OFF_GSUM    164864    // [B]
#define OFF_WX      164992    // [B][K][C] fp32, atomic-accumulated by k_agg

typedef short bf16x8 __attribute__((ext_vector_type(8)));   // 8 bf16 in 4 VGPRs
typedef float f32x16 __attribute__((ext_vector_type(16)));  // MFMA 32x32 accumulator

union U4 { uint4 u; bf16x8 b; };

__device__ __forceinline__ unsigned hi16(float f) { return __float_as_uint(f) >> 16; }
__device__ __forceinline__ unsigned hi16rne(float f) {
  return (__float_as_uint(f) + 0x8000u) >> 16;
}
__device__ __forceinline__ float fromhi(unsigned h) { return __uint_as_float(h << 16); }
// pack two floats' truncated-bf16 into one dword: low16 = bf16(lo), high16 = bf16(hi)
__device__ __forceinline__ unsigned pk(float lo, float hi) {
  return (__float_as_uint(lo) >> 16) | (__float_as_uint(hi) & 0xFFFF0000u);
}

// ---------------------------------------------------------------- kernel 1
// Build pbig (MFMA-fragment order), invsig; zero wsum/gsum/wx. One block per k.
// pbig uint4 index for (k,c): chunk=c>>5, ks=(c&31)>>1, lh=c&1, kh=k>>5:
//   (((chunk*16+ks)*2+kh)*64 + lh*32 + (k&31))
__global__ void k_prep(const float* __restrict__ anchor,
                       const float* __restrict__ sraw,
                       unsigned* __restrict__ pbig,
                       float* __restrict__ invsig,
                       float* __restrict__ wsum,
                       float* __restrict__ gsum,
                       float* __restrict__ wx) {
  const int k = blockIdx.x;
  const int t = threadIdx.x;
  __shared__ float s_is2[C_], s_m[C_];
  __shared__ float red[4];
  float part = 0.f;
#pragma unroll
  for (int r = 0; r < 2; r++) {
    int c = r * 256 + t;
    float a = anchor[k * C_ + c];
    float sg = 1.f / (1.f + __expf(-sraw[k * C_ + c]));
    float is = 1.f / sg;
    float is2 = is * is;
    s_is2[c] = is2;
    s_m[c] = -2.f * a * is2;
    invsig[k * C_ + c] = is;
    part = fmaf(a * a, is2, part);
  }
  float v = part;
#pragma unroll
  for (int off = 32; off; off >>= 1) v += __shfl_down(v, off);
  if ((t & 63) == 0) red[t >> 6] = v;
  __syncthreads();
  float cst = red[0] + red[1] + red[2] + red[3];
  unsigned ch = hi16(cst);
  unsigned clr = hi16rne(cst - fromhi(ch));
#pragma unroll
  for (int r = 0; r < 2; r++) {
    int c = r * 256 + t;
    float is2 = s_is2[c], m = s_m[c];
    unsigned ih = hi16(is2);
    unsigned ilr = hi16rne(is2 - fromhi(ih));
    unsigned mh = hi16(m);
    unsigned mlr = hi16rne(m - fromhi(mh));
    int chunk = c >> 5, ks = (c & 31) >> 1, lh = c & 1;
    int kh = k >> 5;
    size_t dst = ((((size_t)chunk * 16 + ks) * 2 + kh) * 64 + lh * 32 + (k & 31)) * 4;
    pbig[dst + 0] = ih | (ilr << 16);
    pbig[dst + 1] = ih | (mh << 16);
    pbig[dst + 2] = mlr | (mh << 16);
    pbig[dst + 3] = (c == 0) ? (ch | (clr << 16)) : 0u;
  }
  // zero wx slice for this k-block: 8192 floats = 2048 float4
  float4 z4 = make_float4(0.f, 0.f, 0.f, 0.f);
  float4* wz = (float4*)(wx + (size_t)k * 8192);
#pragma unroll
  for (int it = 0; it < 8; it++) wz[it * 256 + t] = z4;
  if (k == 0) {
    for (int i = t; i < B_ * K_; i += 256) wsum[i] = 0.f;
    if (t < B_) gsum[t] = 0.f;
  }
}

// ---------------------------------------------------------------- kernel 2
// MFMA distance GEMM (split-bf16, inner dim 4096) + softmax.
// v8: split-C at 4 waves/SIMD WITHOUT spilling (v7's (256,4) cap spilled the
// 64-VGPR x register dbuf -> 544 MB scratch writes). Fix: x staged in LDS,
// SHARED by all 4 waves (kh pairs read identical columns), freeing those
// VGPRs. Per-wave state: acc 32 + A-frag dbuf 32 + xstage 16 ~= 105 < 128.
// Block = 64 n-cols x full C x full K; waves = (chalf, kh) quarters.
// 8 steps; step = 16KB x-tile (both chalf chunks) LDS-dbuf, 1 barrier/step.
// Epilogue: chalf exchange (LDS overlay on xlds) + cross-kh softmax.
__global__ __launch_bounds__(256, 4) void k_dist(
    const float* __restrict__ x,
    const unsigned* __restrict__ pbig,
    float* __restrict__ soft,
    float* __restrict__ wsum) {
  const int bid = blockIdx.x;
  const int swz = (bid & 7) * 128 + (bid >> 3);  // XCD remap (1024%8==0, bijective)
  const int b = swz >> 6;                        // 16 batches (64 blocks each)
  const int nblk = (swz & 63) * 64;              // 64 n-blocks of 64 cols
  const int tid = threadIdx.x;
  const int wid = tid >> 6;
  const int lane = tid & 63;
  const int l31 = lane & 31;
  const int lh = lane >> 5;
  const int kh = wid & 1;                        // k-half
  const int chalf = wid >> 1;                    // C-half this wave accumulates

  __shared__ float xlds[2][64][64];              // 32 KB x double-buffer
  __shared__ float cmax[4][32];
  __shared__ float csum[4][32];

  f32x16 accA, accB;                             // cols nblk+0..31 / +32..63
#pragma unroll
  for (int i = 0; i < 16; i++) { accA[i] = 0.f; accB[i] = 0.f; }

  const float* xb = x + (size_t)b * (C_ * N_);
  const uint4* pf = (const uint4*)pbig + (size_t)kh * 64 + lane;
  const int cbase = chalf * 8;                   // this wave's first chunk

#define PACKMF(XV, CC, ACC, AFRAG)                                            \
  {                                                                           \
    float xv = (XV);                                                          \
    float x2 = xv * xv;                                                       \
    unsigned u = __float_as_uint(xv);                                         \
    unsigned u2 = __float_as_uint(x2);                                        \
    unsigned uhf = u & 0xFFFF0000u;                                           \
    unsigned u2hf = u2 & 0xFFFF0000u;                                         \
    float xl = xv - __uint_as_float(uhf);                                     \
    float x2l = x2 - __uint_as_float(u2hf);                                   \
    U4 bf;                                                                    \
    bf.u.x = (u2 >> 16) | u2hf;                                               \
    bf.u.y = ((__float_as_uint(x2l) + 0x8000u) >> 16) | uhf;                  \
    bf.u.z = (u >> 16) | ((__float_as_uint(xl) + 0x8000u) & 0xFFFF0000u);     \
    bf.u.w = ((CC) == 0) ? 0x3F803F80u : 0u;                                  \
    ACC = __builtin_amdgcn_mfma_f32_32x32x16_bf16((AFRAG), bf.b, ACC, 0, 0, 0); \
  }

  // staging: element-16B index e = it*256+tid; row cl = e>>4 (0..63:
  // 0-31 = chalf0's chunk s, 32-63 = chalf1's chunk 8+s); nf = e&15.
  // global c = (cl>>5)*256 + s*32 + (cl&31).
  float4 xs[4];

// One step: [load x(s+1)] ; SYNC ; [prefetch A(s+1)] ; compute(buf s&1)
// from LDS + FCUR ; [store x(s+1) -> buf (s+1)&1].  One barrier per step.
#define STEP_BODY(S, FCUR, FNXT)                                              \
  {                                                                           \
    const int s_ = (S);                                                       \
    if (s_ < 7) {                                                             \
      _Pragma("unroll")                                                       \
      for (int it = 0; it < 4; it++) {                                        \
        int e = it * 256 + tid;                                               \
        int cl = e >> 4, nf = e & 15;                                         \
        int cg = (cl >> 5) * 256 + (s_ + 1) * 32 + (cl & 31);                 \
        xs[it] = *(const float4*)(xb + (size_t)cg * N_ + nblk + nf * 4);      \
      }                                                                       \
    }                                                                         \
    __syncthreads();                                                          \
    if (s_ < 7) {                                                             \
      _Pragma("unroll")                                                       \
      for (int kk = 0; kk < 16; kk++)                                         \
        FNXT[kk].u = pf[(size_t)((cbase + s_ + 1) * 16 + kk) * 128];          \
    }                                                                         \
    _Pragma("unroll")                                                         \
    for (int ks = 0; ks < 16; ks++) {                                         \
      const int c = (cbase + s_) * 32 + ks * 2 + lh;                          \
      float xvA = xlds[(S) & 1][chalf * 32 + ks * 2 + lh][l31];               \
      float xvB = xlds[(S) & 1][chalf * 32 + ks * 2 + lh][32 + l31];          \
      PACKMF(xvA, c, accA, FCUR[ks].b);                                       \
      PACKMF(xvB, c, accB, FCUR[ks].b);                                       \
    }                                                                         \
    if (s_ < 7) {                                                             \
      _Pragma("unroll")                                                       \
      for (int it = 0; it < 4; it++) {                                        \
        int e = it * 256 + tid;                                               \
        int cl = e >> 4, nf = e & 15;                                         \
        *(float4*)&xlds[((S) + 1) & 1][cl][nf * 4] = xs[it];                  \
      }                                                                       \
    }                                                                         \
  }

  U4 f0_[16], f1_[16];
  // prologue: stage step 0 into buf0; prefetch step-0 A-frags
#pragma unroll
  for (int it = 0; it < 4; it++) {
    int e = it * 256 + tid;
    int cl = e >> 4, nf = e & 15;
    int cg = (cl >> 5) * 256 + (cl & 31);
    xs[it] = *(const float4*)(xb + (size_t)cg * N_ + nblk + nf * 4);
  }
#pragma unroll
  for (int kk = 0; kk < 16; kk++)
    f0_[kk].u = pf[(size_t)(cbase * 16 + kk) * 128];
#pragma unroll
  for (int it = 0; it < 4; it++) {
    int e = it * 256 + tid;
    int cl = e >> 4, nf = e & 15;
    *(float4*)&xlds[0][cl][nf * 4] = xs[it];
  }

  for (int s2 = 0; s2 < 4; s2++) {
    STEP_BODY(2 * s2,     f0_, f1_);
    STEP_BODY(2 * s2 + 1, f1_, f0_);
  }
#undef STEP_BODY
#undef PACKMF

  // ---- chalf-pair exchange (partner wid^2). exch overlays the now-dead
  // xlds (5120 floats < 8192). ALL STATIC register indices. ----
  __syncthreads();                     // all waves done reading xlds
  float* exch = (float*)xlds;          // [4][64][20]
  {
    float* pw = &exch[(wid * 64 + lane) * 20];
    if (chalf == 0) {
#pragma unroll
      for (int q = 0; q < 4; q++)
        *(float4*)&pw[q * 4] = make_float4(accB[q * 4], accB[q * 4 + 1],
                                           accB[q * 4 + 2], accB[q * 4 + 3]);
    } else {
#pragma unroll
      for (int q = 0; q < 4; q++)
        *(float4*)&pw[q * 4] = make_float4(accA[q * 4], accA[q * 4 + 1],
                                           accA[q * 4 + 2], accA[q * 4 + 3]);
    }
  }
  __syncthreads();
  f32x16 own;
  {
    const float* pr = &exch[((wid ^ 2) * 64 + lane) * 20];
    if (chalf == 0) {
#pragma unroll
      for (int r = 0; r < 16; r++) own[r] = accA[r] + pr[r];
    } else {
#pragma unroll
      for (int r = 0; r < 16; r++) own[r] = accB[r] + pr[r];
    }
  }

  // ---- softmax over k=64: cross-kh partner wid^1 (same col-half). ----
  float* softb = soft + (size_t)b * (K_ * N_);
  float mm = -3.4e38f;
#pragma unroll
  for (int r = 0; r < 16; r++) {
    own[r] *= -0.5f;
    mm = fmaxf(mm, own[r]);
  }
  mm = fmaxf(mm, __shfl_xor(mm, 32));
  cmax[wid][l31] = mm;
  __syncthreads();
  float m = fmaxf(cmax[wid][l31], cmax[wid ^ 1][l31]);
  float ss = 0.f;
#pragma unroll
  for (int r = 0; r < 16; r++) {
    own[r] = __expf(own[r] - m);
    ss += own[r];
  }
  ss += __shfl_xor(ss, 32);
  csum[wid][l31] = ss;
  __syncthreads();
  float inv = 1.f / (csum[wid][l31] + csum[wid ^ 1][l31]);
  const int nc = nblk + chalf * 32 + l31;        // this wave's column
#pragma unroll
  for (int r = 0; r < 16; r++) {
    float w = own[r] * inv;
    own[r] = w;
    int k0 = kh * 32 + (r & 3) + 8 * (r >> 2) + 4 * lh;
    softb[(size_t)k0 * N_ + nc] = w;
  }
  // ---- wsum: reduce own 32 cols, one atomic per k-row ----
#pragma unroll
  for (int r = 0; r < 16; r++) {
    float v = own[r];
    v += __shfl_xor(v, 1);
    v += __shfl_xor(v, 2);
    v += __shfl_xor(v, 4);
    v += __shfl_xor(v, 8);
    v += __shfl_xor(v, 16);
    if (l31 == 0) {
      int k0 = kh * 32 + (r & 3) + 8 * (r >> 2) + 4 * lh;
      atomicAdd(&wsum[b * K_ + k0], v);
    }
  }
}

// ---------------------------------------------------------------- kernel 3
// Aggregation GEMM via MFMA: wx[b,k,c] += sum_n soft[b,k,n]*x[b,c,n].
// (round-8 verified version) n split 4 ways (z), grid 1024 1D with XCD-group
// swizzle. Partials atomicAdd'ed into zero-initialized wx; unroll 2.
__global__ __launch_bounds__(256, 4) void k_agg(const float* __restrict__ x,
                                                const float* __restrict__ soft,
                                                float* __restrict__ wx) {
  const int bid = blockIdx.x;
  const int xcd = bid & 7, slot = bid >> 3;      // 128 slots per XCD
  const int grp = (slot >> 4) * 8 + xcd;         // 0..63 = (b,z) group
  const int ct = slot & 15;
  const int b = grp & 15, z = grp >> 4;
  const int tid = threadIdx.x;
  const int wid = tid >> 6, lane = tid & 63, l31 = lane & 31, lh = lane >> 5;
  const int c0 = ct * 32;
  const int n0 = z * 1024 + wid * 256;
  __shared__ float red[4][64][36];  // stride 36 floats (odd x16B) per lane

  f32x16 acc[2];
#pragma unroll
  for (int kt = 0; kt < 2; kt++)
#pragma unroll
    for (int i = 0; i < 16; i++) acc[kt][i] = 0.f;

  const float* sb = soft + (size_t)b * (K_ * N_);
  const float* xr = x + (size_t)b * (C_ * N_) + (size_t)(c0 + l31) * N_;
  const float* s0 = sb + (size_t)l31 * N_;
  const float* s1 = sb + (size_t)(32 + l31) * N_;

#pragma unroll 2
  for (int kstep = 0; kstep < 16; kstep++) {
    int nb = n0 + kstep * 16 + lh * 8;
    float4 f0 = *(const float4*)&s0[nb];
    float4 f1 = *(const float4*)&s0[nb + 4];
    float4 g0 = *(const float4*)&s1[nb];
    float4 g1 = *(const float4*)&s1[nb + 4];
    float4 h0 = *(const float4*)&xr[nb];
    float4 h1 = *(const float4*)&xr[nb + 4];
    U4 A0, A1, Bf;
    A0.u.x = pk(f0.x, f0.y); A0.u.y = pk(f0.z, f0.w);
    A0.u.z = pk(f1.x, f1.y); A0.u.w = pk(f1.z, f1.w);
    A1.u.x = pk(g0.x, g0.y); A1.u.y = pk(g0.z, g0.w);
    A1.u.z = pk(g1.x, g1.y); A1.u.w = pk(g1.z, g1.w);
    Bf.u.x = pk(h0.x, h0.y); Bf.u.y = pk(h0.z, h0.w);
    Bf.u.z = pk(h1.x, h1.y); Bf.u.w = pk(h1.z, h1.w);
    acc[0] = __builtin_amdgcn_mfma_f32_32x32x16_bf16(A0.b, Bf.b, acc[0], 0, 0, 0);
    acc[1] = __builtin_amdgcn_mfma_f32_32x32x16_bf16(A1.b, Bf.b, acc[1], 0, 0, 0);
  }
  // stash per-wave partials
#pragma unroll
  for (int kt = 0; kt < 2; kt++)
#pragma unroll
    for (int q = 0; q < 4; q++) {
      float4 vv = make_float4(acc[kt][q * 4], acc[kt][q * 4 + 1],
                              acc[kt][q * 4 + 2], acc[kt][q * 4 + 3]);
      *(float4*)&red[wid][lane][kt * 16 + q * 4] = vv;
    }
  __syncthreads();
  // cross-wave reduce + atomic accumulate (2048 outputs, 8 per thread)
  const int lt = tid & 63, sb4 = (tid >> 6) * 8;
  float v[8];
#pragma unroll
  for (int i = 0; i < 8; i++) v[i] = 0.f;
#pragma unroll
  for (int w = 0; w < 4; w++)
#pragma unroll
    for (int i = 0; i < 8; i++) v[i] += red[w][lt][sb4 + i];
#pragma unroll
  for (int i = 0; i < 8; i++) {
    int s = sb4 + i;
    int kt = s >> 4, r = s & 15;
    int k = kt * 32 + (r & 3) + 8 * (r >> 2) + 4 * (lt >> 5);
    atomicAdd(&wx[((size_t)b * K_ + k) * C_ + c0 + (lt & 31)], v[i]);
  }
}

// ---------------------------------------------------------------- kernel 4
// nodes = (wx - wsum*anchor)/sigma/(wsum+eps); intra L2-norm -> out0; gsum.
__global__ void k_nodes(const float* __restrict__ wx,
                        const float* __restrict__ wsum,
                        const float* __restrict__ anchor,
                        const float* __restrict__ invsig,
                        float* __restrict__ out0,
                        float* __restrict__ gsum) {
  const int k = blockIdx.x, b = blockIdx.y;
  const int tid = threadIdx.x;
  float wsv = wsum[b * K_ + k];
  float winv = 1.f / (wsv + 1e-9f);
  float vals[4];
  float local = 0.f;
#pragma unroll
  for (int r = 0; r < 4; r++) {
    int c = r * 128 + tid;
    float w = wx[((size_t)b * K_ + k) * C_ + c];
    float v = (w - wsv * anchor[k * C_ + c]) * invsig[k * C_ + c] * winv;
    vals[r] = v;
    local = fmaf(v, v, local);
  }
  float v = local;
#pragma unroll
  for (int off = 32; off; off >>= 1) v += __shfl_down(v, off);
  __shared__ float red[2];
  if ((tid & 63) == 0) red[tid >> 6] = v;
  __syncthreads();
  float sumsq = red[0] + red[1];
  float norm = sqrtf(sumsq);
  float scale = 1.f / fmaxf(norm, 1e-12f);
#pragma unroll
  for (int r = 0; r < 4; r++) {
    int c = r * 128 + tid;
    out0[((size_t)b * K_ + k) * C_ + c] = vals[r] * scale;
  }
  if (tid == 0) atomicAdd(&gsum[b], sumsq * scale * scale);
}

// ---------------------------------------------------------------- kernel 5
// Global L2 scale in place on out0 ([B][K*C] flat == reference (B,C,K)).
__global__ void k_final(float* __restrict__ out0,
                        const float* __restrict__ gsum) {
  for (int i = blockIdx.x * 256 + threadIdx.x; i < B_ * K_ * C_;
       i += gridDim.x * 256) {
    int b = i >> 15;  // K_*C_ = 32768
    out0[i] = out0[i] * (1.f / fmaxf(sqrtf(gsum[b]), 1e-12f));
  }
}

// ---------------------------------------------------------------- launch
extern "C" void kernel_launch(void* const* d_in, const int* in_sizes, int n_in,
                              void* d_out, int out_size, void* d_ws, size_t ws_size,
                              hipStream_t stream) {
  const float* x = (const float*)d_in[0];       // [B,C,H,W]
  const float* anchor = (const float*)d_in[1];  // [K,C]
  const float* sraw = (const float*)d_in[2];    // [K,C]
  float* out0 = (float*)d_out;                          // [B,C,K] flat
  float* soft = out0 + (size_t)B_ * C_ * K_;            // [B,K,N] (output 1)
  float* ws = (float*)d_ws;

  unsigned* pbig = (unsigned*)(ws + OFF_PBIG);
  float* invsig = ws + OFF_INVSIG;
  float* wsum = ws + OFF_WSUM;
  float* gsum = ws + OFF_GSUM;
  float* wx = ws + OFF_WX;

  k_prep<<<K_, 256, 0, stream>>>(anchor, sraw, pbig, invsig, wsum, gsum, wx);
  k_dist<<<1024, 256, 0, stream>>>(x, pbig, soft, wsum);
  k_agg<<<1024, 256, 0, stream>>>(x, soft, wx);
  k_nodes<<<dim3(K_, B_), 128, 0, stream>>>(wx, wsum, anchor, invsig, out0,
                                            gsum);
  k_final<<<512, 256, 0, stream>>>(out0, gsum);
}

// Round 11
// 310.233 us; speedup vs baseline: 1.8806x; 1.4612x over previous
//
#include <hip/hip_runtime.h>
#include <math.h>

// Problem constants (fixed by reference setup_inputs)
#define B_ 16
#define C_ 512
#define N_ 4096   // 64*64
#define K_ 64

// Workspace layout (float offsets). Total ~689K floats = 2.76 MB.
#define OFF_PBIG    0         // [16 chunk][16 kstep][2 kh][64 lane] uint4 = 512 KB
#define OFF_INVSIG  131072    // [K][C] 1/sigma fp32
#define OFF_WSUM    163840    // [B][K]
#define OFF_GSUM    164864    // [B]
#define OFF_WX      164992    // [B][K][C] fp32, atomic-accumulated by k_agg

typedef short bf16x8 __attribute__((ext_vector_type(8)));   // 8 bf16 in 4 VGPRs
typedef float f32x16 __attribute__((ext_vector_type(16)));  // MFMA 32x32 accumulator

union U4 { uint4 u; bf16x8 b; };

__device__ __forceinline__ unsigned hi16(float f) { return __float_as_uint(f) >> 16; }
__device__ __forceinline__ unsigned hi16rne(float f) {
  return (__float_as_uint(f) + 0x8000u) >> 16;
}
__device__ __forceinline__ float fromhi(unsigned h) { return __uint_as_float(h << 16); }
// pack two floats' truncated-bf16 into one dword: low16 = bf16(lo), high16 = bf16(hi)
__device__ __forceinline__ unsigned pk(float lo, float hi) {
  return (__float_as_uint(lo) >> 16) | (__float_as_uint(hi) & 0xFFFF0000u);
}

// ---------------------------------------------------------------- kernel 1
// Build pbig (MFMA-fragment order), invsig; zero wsum/gsum/wx. One block per k.
// pbig uint4 index for (k,c): chunk=c>>5, ks=(c&31)>>1, lh=c&1, kh=k>>5:
//   (((chunk*16+ks)*2+kh)*64 + lh*32 + (k&31))
__global__ void k_prep(const float* __restrict__ anchor,
                       const float* __restrict__ sraw,
                       unsigned* __restrict__ pbig,
                       float* __restrict__ invsig,
                       float* __restrict__ wsum,
                       float* __restrict__ gsum,
                       float* __restrict__ wx) {
  const int k = blockIdx.x;
  const int t = threadIdx.x;
  __shared__ float s_is2[C_], s_m[C_];
  __shared__ float red[4];
  float part = 0.f;
#pragma unroll
  for (int r = 0; r < 2; r++) {
    int c = r * 256 + t;
    float a = anchor[k * C_ + c];
    float sg = 1.f / (1.f + __expf(-sraw[k * C_ + c]));
    float is = 1.f / sg;
    float is2 = is * is;
    s_is2[c] = is2;
    s_m[c] = -2.f * a * is2;
    invsig[k * C_ + c] = is;
    part = fmaf(a * a, is2, part);
  }
  float v = part;
#pragma unroll
  for (int off = 32; off; off >>= 1) v += __shfl_down(v, off);
  if ((t & 63) == 0) red[t >> 6] = v;
  __syncthreads();
  float cst = red[0] + red[1] + red[2] + red[3];
  unsigned ch = hi16(cst);
  unsigned clr = hi16rne(cst - fromhi(ch));
#pragma unroll
  for (int r = 0; r < 2; r++) {
    int c = r * 256 + t;
    float is2 = s_is2[c], m = s_m[c];
    unsigned ih = hi16(is2);
    unsigned ilr = hi16rne(is2 - fromhi(ih));
    unsigned mh = hi16(m);
    unsigned mlr = hi16rne(m - fromhi(mh));
    int chunk = c >> 5, ks = (c & 31) >> 1, lh = c & 1;
    int kh = k >> 5;
    size_t dst = ((((size_t)chunk * 16 + ks) * 2 + kh) * 64 + lh * 32 + (k & 31)) * 4;
    pbig[dst + 0] = ih | (ilr << 16);
    pbig[dst + 1] = ih | (mh << 16);
    pbig[dst + 2] = mlr | (mh << 16);
    pbig[dst + 3] = (c == 0) ? (ch | (clr << 16)) : 0u;
  }
  // zero wx slice for this k-block: 8192 floats = 2048 float4
  float4 z4 = make_float4(0.f, 0.f, 0.f, 0.f);
  float4* wz = (float4*)(wx + (size_t)k * 8192);
#pragma unroll
  for (int it = 0; it < 8; it++) wz[it * 256 + t] = z4;
  if (k == 0) {
    for (int i = t; i < B_ * K_; i += 256) wsum[i] = 0.f;
    if (t < B_) gsum[t] = 0.f;
  }
}

// ---------------------------------------------------------------- kernel 2
// MFMA distance GEMM (split-bf16, inner dim 4096) + softmax.
// v9: fits 128 VGPR for real. v8's U4 f[16] dbuf = 128 VGPRs alone -> spill
// at the (256,4) cap (WRITE 343 MB). Fixes:
//  - x staged via global_load_lds (width 16): the v8 LDS layout is already
//    wave-uniform-base + lane*16 (linear float off 4e), so no xs registers
//    and no store pass.
//  - A-frag double-buffer at HALF-CHUNK depth 8: f0_[8]/f1_[8] = 64 VGPRs.
// Budget: acc 32 + f 64 + addr ~20 ~= 118 < 128.
// Structure otherwise = v8 (correctness-verified): 4 waves = (chalf,kh),
// 64-col block, 8 steps, 1 barrier/step; chalf-exchange + cross-kh softmax.
__global__ __launch_bounds__(256, 4) void k_dist(
    const float* __restrict__ x,
    const unsigned* __restrict__ pbig,
    float* __restrict__ soft,
    float* __restrict__ wsum) {
  const int bid = blockIdx.x;
  const int swz = (bid & 7) * 128 + (bid >> 3);  // XCD remap (1024%8==0, bijective)
  const int b = swz >> 6;                        // 16 batches (64 blocks each)
  const int nblk = (swz & 63) * 64;              // 64 n-blocks of 64 cols
  const int tid = threadIdx.x;
  const int wid = tid >> 6;
  const int lane = tid & 63;
  const int l31 = lane & 31;
  const int lh = lane >> 5;
  const int kh = wid & 1;                        // k-half
  const int chalf = wid >> 1;                    // C-half this wave accumulates

  __shared__ float xlds[2][64][64];              // 32 KB x double-buffer
  __shared__ float cmax[4][32];
  __shared__ float csum[4][32];

  f32x16 accA, accB;                             // cols nblk+0..31 / +32..63
#pragma unroll
  for (int i = 0; i < 16; i++) { accA[i] = 0.f; accB[i] = 0.f; }

  const float* xb = x + (size_t)b * (C_ * N_);
  const uint4* pf = (const uint4*)pbig + (size_t)kh * 64 + lane;
  const int cbase = chalf * 8;                   // this wave's first chunk

#define PACKMF(XV, CC, ACC, AFRAG)                                            \
  {                                                                           \
    float xv = (XV);                                                          \
    float x2 = xv * xv;                                                       \
    unsigned u = __float_as_uint(xv);                                         \
    unsigned u2 = __float_as_uint(x2);                                        \
    unsigned uhf = u & 0xFFFF0000u;                                           \
    unsigned u2hf = u2 & 0xFFFF0000u;                                         \
    float xl = xv - __uint_as_float(uhf);                                     \
    float x2l = x2 - __uint_as_float(u2hf);                                   \
    U4 bf;                                                                    \
    bf.u.x = (u2 >> 16) | u2hf;                                               \
    bf.u.y = ((__float_as_uint(x2l) + 0x8000u) >> 16) | uhf;                  \
    bf.u.z = (u >> 16) | ((__float_as_uint(xl) + 0x8000u) & 0xFFFF0000u);     \
    bf.u.w = ((CC) == 0) ? 0x3F803F80u : 0u;                                  \
    ACC = __builtin_amdgcn_mfma_f32_32x32x16_bf16((AFRAG), bf.b, ACC, 0, 0, 0); \
  }

  // staging: e = it*256 + tid; row cl = e>>4 (0..31 = chalf0 chunk s,
  // 32..63 = chalf1 chunk 8+s); nf = e&15; c = (cl>>5)*256 + s*32 + (cl&31).
  // LDS linear float offset 4e = uniform(it,wid) base + lane*4 -> exactly
  // global_load_lds's wave-uniform-base + lane*16B pattern.
#define STAGE(S, BUF)                                                         \
  {                                                                           \
    _Pragma("unroll")                                                         \
    for (int it = 0; it < 4; it++) {                                          \
      int e = it * 256 + tid;                                                 \
      int cl = e >> 4, nf = e & 15;                                           \
      int cg = (cl >> 5) * 256 + (S) * 32 + (cl & 31);                        \
      const float* gsrc = xb + (size_t)cg * N_ + nblk + nf * 4;               \
      float* ldst = (float*)xlds + (size_t)(BUF) * 4096 +                     \
                    (size_t)(it * 256 + wid * 64) * 4;                        \
      __builtin_amdgcn_global_load_lds(                                       \
          (const __attribute__((address_space(1))) void*)gsrc,                \
          (__attribute__((address_space(3))) void*)ldst, 16, 0, 0);           \
    }                                                                         \
  }

  U4 f0_[8], f1_[8];
  // prologue: stage step 0 into buf0 (async); prefetch first half-chunk A-frags
  STAGE(0, 0);
#pragma unroll
  for (int kk = 0; kk < 8; kk++)
    f0_[kk].u = pf[(size_t)(cbase * 16 + kk) * 128];
  __syncthreads();                               // drains vmcnt before barrier

  for (int s = 0; s < 8; s++) {
    if (s < 7) STAGE(s + 1, (s + 1) & 1);        // async into other buffer
    // half A: prefetch f1_ (ks 8..15 this chunk); compute ks 0..7 with f0_
#pragma unroll
    for (int kk = 0; kk < 8; kk++)
      f1_[kk].u = pf[(size_t)((cbase + s) * 16 + 8 + kk) * 128];
#pragma unroll
    for (int ks = 0; ks < 8; ks++) {
      const int c = (cbase + s) * 32 + ks * 2 + lh;
      float xvA = xlds[s & 1][chalf * 32 + ks * 2 + lh][l31];
      float xvB = xlds[s & 1][chalf * 32 + ks * 2 + lh][32 + l31];
      PACKMF(xvA, c, accA, f0_[ks].b);
      PACKMF(xvB, c, accB, f0_[ks].b);
    }
    // half B: prefetch f0_ (ks 0..7 next chunk); compute ks 8..15 with f1_
    if (s < 7) {
#pragma unroll
      for (int kk = 0; kk < 8; kk++)
        f0_[kk].u = pf[(size_t)((cbase + s + 1) * 16 + kk) * 128];
    }
#pragma unroll
    for (int ks = 0; ks < 8; ks++) {
      const int c = (cbase + s) * 32 + (8 + ks) * 2 + lh;
      float xvA = xlds[s & 1][chalf * 32 + (8 + ks) * 2 + lh][l31];
      float xvB = xlds[s & 1][chalf * 32 + (8 + ks) * 2 + lh][32 + l31];
      PACKMF(xvA, c, accA, f1_[ks].b);
      PACKMF(xvB, c, accB, f1_[ks].b);
    }
    __syncthreads();   // next-step stage complete + everyone done with buf[s&1]
  }
#undef STAGE
#undef PACKMF

  // ---- chalf-pair exchange (partner wid^2). exch overlays the now-dead
  // xlds. ALL STATIC register indices (v8-verified pattern). ----
  float* exch = (float*)xlds;          // [4][64][20]
  {
    float* pw = &exch[(wid * 64 + lane) * 20];
    if (chalf == 0) {
#pragma unroll
      for (int q = 0; q < 4; q++)
        *(float4*)&pw[q * 4] = make_float4(accB[q * 4], accB[q * 4 + 1],
                                           accB[q * 4 + 2], accB[q * 4 + 3]);
    } else {
#pragma unroll
      for (int q = 0; q < 4; q++)
        *(float4*)&pw[q * 4] = make_float4(accA[q * 4], accA[q * 4 + 1],
                                           accA[q * 4 + 2], accA[q * 4 + 3]);
    }
  }
  __syncthreads();
  f32x16 own;
  {
    const float* pr = &exch[((wid ^ 2) * 64 + lane) * 20];
    if (chalf == 0) {
#pragma unroll
      for (int r = 0; r < 16; r++) own[r] = accA[r] + pr[r];
    } else {
#pragma unroll
      for (int r = 0; r < 16; r++) own[r] = accB[r] + pr[r];
    }
  }

  // ---- softmax over k=64: cross-kh partner wid^1 (same col-half). ----
  float* softb = soft + (size_t)b * (K_ * N_);
  float mm = -3.4e38f;
#pragma unroll
  for (int r = 0; r < 16; r++) {
    own[r] *= -0.5f;
    mm = fmaxf(mm, own[r]);
  }
  mm = fmaxf(mm, __shfl_xor(mm, 32));
  cmax[wid][l31] = mm;
  __syncthreads();
  float m = fmaxf(cmax[wid][l31], cmax[wid ^ 1][l31]);
  float ss = 0.f;
#pragma unroll
  for (int r = 0; r < 16; r++) {
    own[r] = __expf(own[r] - m);
    ss += own[r];
  }
  ss += __shfl_xor(ss, 32);
  csum[wid][l31] = ss;
  __syncthreads();
  float inv = 1.f / (csum[wid][l31] + csum[wid ^ 1][l31]);
  const int nc = nblk + chalf * 32 + l31;        // this wave's column
#pragma unroll
  for (int r = 0; r < 16; r++) {
    float w = own[r] * inv;
    own[r] = w;
    int k0 = kh * 32 + (r & 3) + 8 * (r >> 2) + 4 * lh;
    softb[(size_t)k0 * N_ + nc] = w;
  }
  // ---- wsum: reduce own 32 cols, one atomic per k-row ----
#pragma unroll
  for (int r = 0; r < 16; r++) {
    float v = own[r];
    v += __shfl_xor(v, 1);
    v += __shfl_xor(v, 2);
    v += __shfl_xor(v, 4);
    v += __shfl_xor(v, 8);
    v += __shfl_xor(v, 16);
    if (l31 == 0) {
      int k0 = kh * 32 + (r & 3) + 8 * (r >> 2) + 4 * lh;
      atomicAdd(&wsum[b * K_ + k0], v);
    }
  }
}

// ---------------------------------------------------------------- kernel 3
// Aggregation GEMM via MFMA: wx[b,k,c] += sum_n soft[b,k,n]*x[b,c,n].
// (round-8 verified version) n split 4 ways (z), grid 1024 1D with XCD-group
// swizzle. Partials atomicAdd'ed into zero-initialized wx; unroll 2.
__global__ __launch_bounds__(256, 4) void k_agg(const float* __restrict__ x,
                                                const float* __restrict__ soft,
                                                float* __restrict__ wx) {
  const int bid = blockIdx.x;
  const int xcd = bid & 7, slot = bid >> 3;      // 128 slots per XCD
  const int grp = (slot >> 4) * 8 + xcd;         // 0..63 = (b,z) group
  const int ct = slot & 15;
  const int b = grp & 15, z = grp >> 4;
  const int tid = threadIdx.x;
  const int wid = tid >> 6, lane = tid & 63, l31 = lane & 31, lh = lane >> 5;
  const int c0 = ct * 32;
  const int n0 = z * 1024 + wid * 256;
  __shared__ float red[4][64][36];  // stride 36 floats (odd x16B) per lane

  f32x16 acc[2];
#pragma unroll
  for (int kt = 0; kt < 2; kt++)
#pragma unroll
    for (int i = 0; i < 16; i++) acc[kt][i] = 0.f;

  const float* sb = soft + (size_t)b * (K_ * N_);
  const float* xr = x + (size_t)b * (C_ * N_) + (size_t)(c0 + l31) * N_;
  const float* s0 = sb + (size_t)l31 * N_;
  const float* s1 = sb + (size_t)(32 + l31) * N_;

#pragma unroll 2
  for (int kstep = 0; kstep < 16; kstep++) {
    int nb = n0 + kstep * 16 + lh * 8;
    float4 f0 = *(const float4*)&s0[nb];
    float4 f1 = *(const float4*)&s0[nb + 4];
    float4 g0 = *(const float4*)&s1[nb];
    float4 g1 = *(const float4*)&s1[nb + 4];
    float4 h0 = *(const float4*)&xr[nb];
    float4 h1 = *(const float4*)&xr[nb + 4];
    U4 A0, A1, Bf;
    A0.u.x = pk(f0.x, f0.y); A0.u.y = pk(f0.z, f0.w);
    A0.u.z = pk(f1.x, f1.y); A0.u.w = pk(f1.z, f1.w);
    A1.u.x = pk(g0.x, g0.y); A1.u.y = pk(g0.z, g0.w);
    A1.u.z = pk(g1.x, g1.y); A1.u.w = pk(g1.z, g1.w);
    Bf.u.x = pk(h0.x, h0.y); Bf.u.y = pk(h0.z, h0.w);
    Bf.u.z = pk(h1.x, h1.y); Bf.u.w = pk(h1.z, h1.w);
    acc[0] = __builtin_amdgcn_mfma_f32_32x32x16_bf16(A0.b, Bf.b, acc[0], 0, 0, 0);
    acc[1] = __builtin_amdgcn_mfma_f32_32x32x16_bf16(A1.b, Bf.b, acc[1], 0, 0, 0);
  }
  // stash per-wave partials
#pragma unroll
  for (int kt = 0; kt < 2; kt++)
#pragma unroll
    for (int q = 0; q < 4; q++) {
      float4 vv = make_float4(acc[kt][q * 4], acc[kt][q * 4 + 1],
                              acc[kt][q * 4 + 2], acc[kt][q * 4 + 3]);
      *(float4*)&red[wid][lane][kt * 16 + q * 4] = vv;
    }
  __syncthreads();
  // cross-wave reduce + atomic accumulate (2048 outputs, 8 per thread)
  const int lt = tid & 63, sb4 = (tid >> 6) * 8;
  float v[8];
#pragma unroll
  for (int i = 0; i < 8; i++) v[i] = 0.f;
#pragma unroll
  for (int w = 0; w < 4; w++)
#pragma unroll
    for (int i = 0; i < 8; i++) v[i] += red[w][lt][sb4 + i];
#pragma unroll
  for (int i = 0; i < 8; i++) {
    int s = sb4 + i;
    int kt = s >> 4, r = s & 15;
    int k = kt * 32 + (r & 3) + 8 * (r >> 2) + 4 * (lt >> 5);
    atomicAdd(&wx[((size_t)b * K_ + k) * C_ + c0 + (lt & 31)], v[i]);
  }
}

// ---------------------------------------------------------------- kernel 4
// nodes = (wx - wsum*anchor)/sigma/(wsum+eps); intra L2-norm -> out0; gsum.
__global__ void k_nodes(const float* __restrict__ wx,
                        const float* __restrict__ wsum,
                        const float* __restrict__ anchor,
                        const float* __restrict__ invsig,
                        float* __restrict__ out0,
                        float* __restrict__ gsum) {
  const int k = blockIdx.x, b = blockIdx.y;
  const int tid = threadIdx.x;
  float wsv = wsum[b * K_ + k];
  float winv = 1.f / (wsv + 1e-9f);
  float vals[4];
  float local = 0.f;
#pragma unroll
  for (int r = 0; r < 4; r++) {
    int c = r * 128 + tid;
    float w = wx[((size_t)b * K_ + k) * C_ + c];
    float v = (w - wsv * anchor[k * C_ + c]) * invsig[k * C_ + c] * winv;
    vals[r] = v;
    local = fmaf(v, v, local);
  }
  float v = local;
#pragma unroll
  for (int off = 32; off; off >>= 1) v += __shfl_down(v, off);
  __shared__ float red[2];
  if ((tid & 63) == 0) red[tid >> 6] = v;
  __syncthreads();
  float sumsq = red[0] + red[1];
  float norm = sqrtf(sumsq);
  float scale = 1.f / fmaxf(norm, 1e-12f);
#pragma unroll
  for (int r = 0; r < 4; r++) {
    int c = r * 128 + tid;
    out0[((size_t)b * K_ + k) * C_ + c] = vals[r] * scale;
  }
  if (tid == 0) atomicAdd(&gsum[b], sumsq * scale * scale);
}

// ---------------------------------------------------------------- kernel 5
// Global L2 scale in place on out0 ([B][K*C] flat == reference (B,C,K)).
__global__ void k_final(float* __restrict__ out0,
                        const float* __restrict__ gsum) {
  for (int i = blockIdx.x * 256 + threadIdx.x; i < B_ * K_ * C_;
       i += gridDim.x * 256) {
    int b = i >> 15;  // K_*C_ = 32768
    out0[i] = out0[i] * (1.f / fmaxf(sqrtf(gsum[b]), 1e-12f));
  }
}

// ---------------------------------------------------------------- launch
extern "C" void kernel_launch(void* const* d_in, const int* in_sizes, int n_in,
                              void* d_out, int out_size, void* d_ws, size_t ws_size,
                              hipStream_t stream) {
  const float* x = (const float*)d_in[0];       // [B,C,H,W]
  const float* anchor = (const float*)d_in[1];  // [K,C]
  const float* sraw = (const float*)d_in[2];    // [K,C]
  float* out0 = (float*)d_out;                          // [B,C,K] flat
  float* soft = out0 + (size_t)B_ * C_ * K_;            // [B,K,N] (output 1)
  float* ws = (float*)d_ws;

  unsigned* pbig = (unsigned*)(ws + OFF_PBIG);
  float* invsig = ws + OFF_INVSIG;
  float* wsum = ws + OFF_WSUM;
  float* gsum = ws + OFF_GSUM;
  float* wx = ws + OFF_WX;

  k_prep<<<K_, 256, 0, stream>>>(anchor, sraw, pbig, invsig, wsum, gsum, wx);
  k_dist<<<1024, 256, 0, stream>>>(x, pbig, soft, wsum);
  k_agg<<<1024, 256, 0, stream>>>(x, soft, wx);
  k_nodes<<<dim3(K_, B_), 128, 0, stream>>>(wx, wsum, anchor, invsig, out0,
                                            gsum);
  k_final<<<512, 256, 0, stream>>>(out0, gsum);
}

// Round 12
// 291.959 us; speedup vs baseline: 1.9983x; 1.0626x over previous
//
#include <hip/hip_runtime.h>
#include <math.h>

// Problem constants (fixed by reference setup_inputs)
#define B_ 16
#define C_ 512
#define N_ 4096   // 64*64
#define K_ 64

// Workspace layout (float offsets). Total ~689K floats = 2.76 MB.
#define OFF_PBIG    0         // [16 chunk][16 kstep][2 kh][64 lane] uint4 = 512 KB
#define OFF_INVSIG  131072    // [K][C] 1/sigma fp32
#define OFF_WSUM    163840    // [B][K]
#define OFF_GSUM    164864    // [B]
#define OFF_WX      164992    // [B][K][C] fp32, atomic-accumulated by k_agg

typedef short bf16x8 __attribute__((ext_vector_type(8)));   // 8 bf16 in 4 VGPRs
typedef float f32x16 __attribute__((ext_vector_type(16)));  // MFMA 32x32 accumulator

union U4 { uint4 u; bf16x8 b; };

__device__ __forceinline__ unsigned hi16(float f) { return __float_as_uint(f) >> 16; }
__device__ __forceinline__ unsigned hi16rne(float f) {
  return (__float_as_uint(f) + 0x8000u) >> 16;
}
__device__ __forceinline__ float fromhi(unsigned h) { return __uint_as_float(h << 16); }
// pack two floats' truncated-bf16 into one dword: low16 = bf16(lo), high16 = bf16(hi)
__device__ __forceinline__ unsigned pk(float lo, float hi) {
  return (__float_as_uint(lo) >> 16) | (__float_as_uint(hi) & 0xFFFF0000u);
}

// ---------------------------------------------------------------- kernel 1
// Build pbig (MFMA-fragment order), invsig; zero wsum/gsum/wx. One block per k.
// pbig uint4 index for (k,c): chunk=c>>5, ks=(c&31)>>1, lh=c&1, kh=k>>5:
//   (((chunk*16+ks)*2+kh)*64 + lh*32 + (k&31))
__global__ void k_prep(const float* __restrict__ anchor,
                       const float* __restrict__ sraw,
                       unsigned* __restrict__ pbig,
                       float* __restrict__ invsig,
                       float* __restrict__ wsum,
                       float* __restrict__ gsum,
                       float* __restrict__ wx) {
  const int k = blockIdx.x;
  const int t = threadIdx.x;
  __shared__ float s_is2[C_], s_m[C_];
  __shared__ float red[4];
  float part = 0.f;
#pragma unroll
  for (int r = 0; r < 2; r++) {
    int c = r * 256 + t;
    float a = anchor[k * C_ + c];
    float sg = 1.f / (1.f + __expf(-sraw[k * C_ + c]));
    float is = 1.f / sg;
    float is2 = is * is;
    s_is2[c] = is2;
    s_m[c] = -2.f * a * is2;
    invsig[k * C_ + c] = is;
    part = fmaf(a * a, is2, part);
  }
  float v = part;
#pragma unroll
  for (int off = 32; off; off >>= 1) v += __shfl_down(v, off);
  if ((t & 63) == 0) red[t >> 6] = v;
  __syncthreads();
  float cst = red[0] + red[1] + red[2] + red[3];
  unsigned ch = hi16(cst);
  unsigned clr = hi16rne(cst - fromhi(ch));
#pragma unroll
  for (int r = 0; r < 2; r++) {
    int c = r * 256 + t;
    float is2 = s_is2[c], m = s_m[c];
    unsigned ih = hi16(is2);
    unsigned ilr = hi16rne(is2 - fromhi(ih));
    unsigned mh = hi16(m);
    unsigned mlr = hi16rne(m - fromhi(mh));
    int chunk = c >> 5, ks = (c & 31) >> 1, lh = c & 1;
    int kh = k >> 5;
    size_t dst = ((((size_t)chunk * 16 + ks) * 2 + kh) * 64 + lh * 32 + (k & 31)) * 4;
    pbig[dst + 0] = ih | (ilr << 16);
    pbig[dst + 1] = ih | (mh << 16);
    pbig[dst + 2] = mlr | (mh << 16);
    pbig[dst + 3] = (c == 0) ? (ch | (clr << 16)) : 0u;
  }
  // zero wx slice for this k-block: 8192 floats = 2048 float4
  float4 z4 = make_float4(0.f, 0.f, 0.f, 0.f);
  float4* wz = (float4*)(wx + (size_t)k * 8192);
#pragma unroll
  for (int it = 0; it < 8; it++) wz[it * 256 + t] = z4;
  if (k == 0) {
    for (int i = t; i < B_ * K_; i += 256) wsum[i] = 0.f;
    if (t < B_) gsum[t] = 0.f;
  }
}

// ---------------------------------------------------------------- kernel 2
// MFMA distance GEMM (split-bf16, inner dim 4096) + softmax.
// v6 VERBATIM (measured 83.6 us, round 8): explicit register pipeline.
// Wave tile 32k x 64n: each A-fragment feeds TWO MFMA chains (accA/accB).
// A-frags AND x double-buffered in named register arrays (all-static
// indices) so 48 loads are in flight while the current chunk computes.
// Grid 512 (XCD-swizzled), 4 waves/block, launch_bounds(256,2).
// NOTE (r9-r11): 4-waves/SIMD variants (split-C, LDS-staged x) all measured
// SLOWER (100-235 us) -- spill at the 128-VGPR cap or barrier-schedule cost.
// This 2-block/CU deep-pipeline structure is the verified local optimum.
__global__ __launch_bounds__(256, 2) void k_dist(
    const float* __restrict__ x,
    const unsigned* __restrict__ pbig,
    float* __restrict__ soft,
    float* __restrict__ wsum) {
  const int bid = blockIdx.x;
  const int swz = (bid & 7) * 64 + (bid >> 3);   // XCD-contiguous remap (512%8==0)
  const int b = swz >> 5;                        // 16 batches
  const int nblk = (swz & 31) * 128;             // 32 n-blocks of 128
  const int tid = threadIdx.x;
  const int wid = tid >> 6;
  const int lane = tid & 63;
  const int l31 = lane & 31;
  const int lh = lane >> 5;
  const int kh = wid & 1;                        // this wave's k-half
  const int n0 = nblk + (wid >> 1) * 64;         // wave's 64 n-columns

  __shared__ float cmax[4][2][32];
  __shared__ float csum[4][2][32];

  f32x16 accA, accB;
#pragma unroll
  for (int i = 0; i < 16; i++) { accA[i] = 0.f; accB[i] = 0.f; }

  const float* xcol0 = x + (size_t)b * (C_ * N_) + n0 + l31;
  const float* xcol1 = xcol0 + 32;
  const uint4* pf = (const uint4*)pbig + (size_t)kh * 64 + lane;

#define PACKMF(XV, CC, ACC, AFRAG)                                            \
  {                                                                           \
    float xv = (XV);                                                          \
    float x2 = xv * xv;                                                       \
    unsigned u = __float_as_uint(xv);                                         \
    unsigned u2 = __float_as_uint(x2);                                        \
    unsigned uhf = u & 0xFFFF0000u;                                           \
    unsigned u2hf = u2 & 0xFFFF0000u;                                         \
    float xl = xv - __uint_as_float(uhf);                                     \
    float x2l = x2 - __uint_as_float(u2hf);                                   \
    U4 bf;                                                                    \
    bf.u.x = (u2 >> 16) | u2hf;                                               \
    bf.u.y = ((__float_as_uint(x2l) + 0x8000u) >> 16) | uhf;                  \
    bf.u.z = (u >> 16) | ((__float_as_uint(xl) + 0x8000u) & 0xFFFF0000u);     \
    bf.u.w = ((CC) == 0) ? 0x3F803F80u : 0u;                                  \
    ACC = __builtin_amdgcn_mfma_f32_32x32x16_bf16((AFRAG), bf.b, ACC, 0, 0, 0); \
  }

// One chunk: optionally prefetch chunk+1 into FNXT/XN*, then 16 ksteps
// consuming FCUR/XC* (each A-frag feeds both acc chains).
#define CHUNK_BODY(CHUNK, FCUR, FNXT, XC0, XC1, XN0, XN1, PREFETCH)           \
  {                                                                           \
    const int chunk_ = (CHUNK);                                               \
    if (PREFETCH) {                                                           \
      _Pragma("unroll")                                                       \
      for (int kk = 0; kk < 16; kk++) {                                       \
        FNXT[kk].u = pf[(size_t)((chunk_ + 1) * 16 + kk) * 128];              \
        XN0[kk] = xcol0[(size_t)((chunk_ + 1) * 32 + kk * 2 + lh) * N_];      \
        XN1[kk] = xcol1[(size_t)((chunk_ + 1) * 32 + kk * 2 + lh) * N_];      \
      }                                                                       \
    }                                                                         \
    _Pragma("unroll")                                                         \
    for (int ks = 0; ks < 16; ks++) {                                         \
      const int c = chunk_ * 32 + ks * 2 + lh;                                \
      PACKMF(XC0[ks], c, accA, FCUR[ks].b);                                   \
      PACKMF(XC1[ks], c, accB, FCUR[ks].b);                                   \
    }                                                                         \
  }

  U4 f0_[16], f1_[16];
  float a0_[16], a1_[16], b0_[16], b1_[16];
#pragma unroll
  for (int kk = 0; kk < 16; kk++) {
    f0_[kk].u = pf[(size_t)kk * 128];
    a0_[kk] = xcol0[(size_t)(kk * 2 + lh) * N_];
    a1_[kk] = xcol1[(size_t)(kk * 2 + lh) * N_];
  }
  for (int c2 = 0; c2 < 8; c2++) {
    CHUNK_BODY(2 * c2,     f0_, f1_, a0_, a1_, b0_, b1_, 1);
    CHUNK_BODY(2 * c2 + 1, f1_, f0_, b0_, b1_, a0_, a1_, (c2 < 7));
  }
#undef CHUNK_BODY
#undef PACKMF

  // ---- softmax over k=64: in-wave (rows via lane^32) then cross-wave
  // (k-half partner wid^1) via tiny LDS max/sum arrays. Two n-columns. ----
  float* softb = soft + (size_t)b * (K_ * N_);
  float mA = -3.4e38f, mB = -3.4e38f;
#pragma unroll
  for (int r = 0; r < 16; r++) {
    accA[r] *= -0.5f; mA = fmaxf(mA, accA[r]);
    accB[r] *= -0.5f; mB = fmaxf(mB, accB[r]);
  }
  mA = fmaxf(mA, __shfl_xor(mA, 32));
  mB = fmaxf(mB, __shfl_xor(mB, 32));
  cmax[wid][0][l31] = mA;
  cmax[wid][1][l31] = mB;
  __syncthreads();
  mA = fmaxf(cmax[wid][0][l31], cmax[wid ^ 1][0][l31]);
  mB = fmaxf(cmax[wid][1][l31], cmax[wid ^ 1][1][l31]);
  float sA = 0.f, sB = 0.f;
#pragma unroll
  for (int r = 0; r < 16; r++) {
    accA[r] = __expf(accA[r] - mA); sA += accA[r];
    accB[r] = __expf(accB[r] - mB); sB += accB[r];
  }
  sA += __shfl_xor(sA, 32);
  sB += __shfl_xor(sB, 32);
  csum[wid][0][l31] = sA;
  csum[wid][1][l31] = sB;
  __syncthreads();
  float invA = 1.f / (csum[wid][0][l31] + csum[wid ^ 1][0][l31]);
  float invB = 1.f / (csum[wid][1][l31] + csum[wid ^ 1][1][l31]);
  const int nc0 = n0 + l31;
#pragma unroll
  for (int r = 0; r < 16; r++) {
    int k0 = kh * 32 + (r & 3) + 8 * (r >> 2) + 4 * lh;
    float wA = accA[r] * invA; accA[r] = wA;
    softb[(size_t)k0 * N_ + nc0] = wA;
    float wB = accB[r] * invB; accB[r] = wB;
    softb[(size_t)k0 * N_ + nc0 + 32] = wB;
  }
  // ---- wsum: both columns belong to b; reduce over 32 lanes, one atomic ----
#pragma unroll
  for (int r = 0; r < 16; r++) {
    float v = accA[r] + accB[r];
    v += __shfl_xor(v, 1);
    v += __shfl_xor(v, 2);
    v += __shfl_xor(v, 4);
    v += __shfl_xor(v, 8);
    v += __shfl_xor(v, 16);
    if (l31 == 0) {
      int k0 = kh * 32 + (r & 3) + 8 * (r >> 2) + 4 * lh;
      atomicAdd(&wsum[b * K_ + k0], v);
    }
  }
}

// ---------------------------------------------------------------- kernel 3
// Aggregation GEMM via MFMA: wx[b,k,c] += sum_n soft[b,k,n]*x[b,c,n].
// v10: the v6 lesson applied here -- explicit named register double-buffer
// (fA/fB, 6 float4 each, all-static) so each kstep's 6 loads are issued one
// kstep ahead instead of consumed immediately (k_dist v5->v6: 118->83.6 us
// from exactly this change). launch_bounds(256,3): VGPR cap ~168 >> ~105
// needed, 3 blocks/CU x 4 waves = 12 waves/CU. Grid/epilogue/atomics
// unchanged from the round-8-verified version (z=4, grid 1024).
__global__ __launch_bounds__(256, 3) void k_agg(const float* __restrict__ x,
                                                const float* __restrict__ soft,
                                                float* __restrict__ wx) {
  const int bid = blockIdx.x;
  const int xcd = bid & 7, slot = bid >> 3;      // 128 slots per XCD
  const int grp = (slot >> 4) * 8 + xcd;         // 0..63 = (b,z) group
  const int ct = slot & 15;
  const int b = grp & 15, z = grp >> 4;
  const int tid = threadIdx.x;
  const int wid = tid >> 6, lane = tid & 63, l31 = lane & 31, lh = lane >> 5;
  const int c0 = ct * 32;
  const int n0 = z * 1024 + wid * 256;
  __shared__ float red[4][64][36];  // stride 36 floats (odd x16B) per lane

  f32x16 acc[2];
#pragma unroll
  for (int kt = 0; kt < 2; kt++)
#pragma unroll
    for (int i = 0; i < 16; i++) acc[kt][i] = 0.f;

  const float* sb = soft + (size_t)b * (K_ * N_);
  const float* xr = x + (size_t)b * (C_ * N_) + (size_t)(c0 + l31) * N_;
  const float* s0 = sb + (size_t)l31 * N_;
  const float* s1 = sb + (size_t)(32 + l31) * N_;

#define LOADK(DST, KS)                                                        \
  {                                                                           \
    int nb = n0 + (KS) * 16 + lh * 8;                                         \
    DST[0] = *(const float4*)&s0[nb];                                         \
    DST[1] = *(const float4*)&s0[nb + 4];                                     \
    DST[2] = *(const float4*)&s1[nb];                                         \
    DST[3] = *(const float4*)&s1[nb + 4];                                     \
    DST[4] = *(const float4*)&xr[nb];                                         \
    DST[5] = *(const float4*)&xr[nb + 4];                                     \
  }
#define COMPK(SRC)                                                            \
  {                                                                           \
    U4 A0, A1, Bf;                                                            \
    A0.u.x = pk(SRC[0].x, SRC[0].y); A0.u.y = pk(SRC[0].z, SRC[0].w);         \
    A0.u.z = pk(SRC[1].x, SRC[1].y); A0.u.w = pk(SRC[1].z, SRC[1].w);         \
    A1.u.x = pk(SRC[2].x, SRC[2].y); A1.u.y = pk(SRC[2].z, SRC[2].w);         \
    A1.u.z = pk(SRC[3].x, SRC[3].y); A1.u.w = pk(SRC[3].z, SRC[3].w);         \
    Bf.u.x = pk(SRC[4].x, SRC[4].y); Bf.u.y = pk(SRC[4].z, SRC[4].w);         \
    Bf.u.z = pk(SRC[5].x, SRC[5].y); Bf.u.w = pk(SRC[5].z, SRC[5].w);         \
    acc[0] = __builtin_amdgcn_mfma_f32_32x32x16_bf16(A0.b, Bf.b, acc[0], 0, 0, 0); \
    acc[1] = __builtin_amdgcn_mfma_f32_32x32x16_bf16(A1.b, Bf.b, acc[1], 0, 0, 0); \
  }

  float4 fA[6], fB[6];
  LOADK(fA, 0);
  for (int k2 = 0; k2 < 8; k2++) {
    LOADK(fB, 2 * k2 + 1);
    COMPK(fA);
    if (k2 < 7) LOADK(fA, 2 * k2 + 2);
    COMPK(fB);
  }
#undef LOADK
#undef COMPK

  // stash per-wave partials
#pragma unroll
  for (int kt = 0; kt < 2; kt++)
#pragma unroll
    for (int q = 0; q < 4; q++) {
      float4 vv = make_float4(acc[kt][q * 4], acc[kt][q * 4 + 1],
                              acc[kt][q * 4 + 2], acc[kt][q * 4 + 3]);
      *(float4*)&red[wid][lane][kt * 16 + q * 4] = vv;
    }
  __syncthreads();
  // cross-wave reduce + atomic accumulate (2048 outputs, 8 per thread)
  const int lt = tid & 63, sb4 = (tid >> 6) * 8;
  float v[8];
#pragma unroll
  for (int i = 0; i < 8; i++) v[i] = 0.f;
#pragma unroll
  for (int w = 0; w < 4; w++)
#pragma unroll
    for (int i = 0; i < 8; i++) v[i] += red[w][lt][sb4 + i];
#pragma unroll
  for (int i = 0; i < 8; i++) {
    int s = sb4 + i;
    int kt = s >> 4, r = s & 15;
    int k = kt * 32 + (r & 3) + 8 * (r >> 2) + 4 * (lt >> 5);
    atomicAdd(&wx[((size_t)b * K_ + k) * C_ + c0 + (lt & 31)], v[i]);
  }
}

// ---------------------------------------------------------------- kernel 4
// nodes = (wx - wsum*anchor)/sigma/(wsum+eps); intra L2-norm -> out0; gsum.
__global__ void k_nodes(const float* __restrict__ wx,
                        const float* __restrict__ wsum,
                        const float* __restrict__ anchor,
                        const float* __restrict__ invsig,
                        float* __restrict__ out0,
                        float* __restrict__ gsum) {
  const int k = blockIdx.x, b = blockIdx.y;
  const int tid = threadIdx.x;
  float wsv = wsum[b * K_ + k];
  float winv = 1.f / (wsv + 1e-9f);
  float vals[4];
  float local = 0.f;
#pragma unroll
  for (int r = 0; r < 4; r++) {
    int c = r * 128 + tid;
    float w = wx[((size_t)b * K_ + k) * C_ + c];
    float v = (w - wsv * anchor[k * C_ + c]) * invsig[k * C_ + c] * winv;
    vals[r] = v;
    local = fmaf(v, v, local);
  }
  float v = local;
#pragma unroll
  for (int off = 32; off; off >>= 1) v += __shfl_down(v, off);
  __shared__ float red[2];
  if ((tid & 63) == 0) red[tid >> 6] = v;
  __syncthreads();
  float sumsq = red[0] + red[1];
  float norm = sqrtf(sumsq);
  float scale = 1.f / fmaxf(norm, 1e-12f);
#pragma unroll
  for (int r = 0; r < 4; r++) {
    int c = r * 128 + tid;
    out0[((size_t)b * K_ + k) * C_ + c] = vals[r] * scale;
  }
  if (tid == 0) atomicAdd(&gsum[b], sumsq * scale * scale);
}

// ---------------------------------------------------------------- kernel 5
// Global L2 scale in place on out0 ([B][K*C] flat == reference (B,C,K)).
__global__ void k_final(float* __restrict__ out0,
                        const float* __restrict__ gsum) {
  for (int i = blockIdx.x * 256 + threadIdx.x; i < B_ * K_ * C_;
       i += gridDim.x * 256) {
    int b = i >> 15;  // K_*C_ = 32768
    out0[i] = out0[i] * (1.f / fmaxf(sqrtf(gsum[b]), 1e-12f));
  }
}

// ---------------------------------------------------------------- launch
extern "C" void kernel_launch(void* const* d_in, const int* in_sizes, int n_in,
                              void* d_out, int out_size, void* d_ws, size_t ws_size,
                              hipStream_t stream) {
  const float* x = (const float*)d_in[0];       // [B,C,H,W]
  const float* anchor = (const float*)d_in[1];  // [K,C]
  const float* sraw = (const float*)d_in[2];    // [K,C]
  float* out0 = (float*)d_out;                          // [B,C,K] flat
  float* soft = out0 + (size_t)B_ * C_ * K_;            // [B,K,N] (output 1)
  float* ws = (float*)d_ws;

  unsigned* pbig = (unsigned*)(ws + OFF_PBIG);
  float* invsig = ws + OFF_INVSIG;
  float* wsum = ws + OFF_WSUM;
  float* gsum = ws + OFF_GSUM;
  float* wx = ws + OFF_WX;

  k_prep<<<K_, 256, 0, stream>>>(anchor, sraw, pbig, invsig, wsum, gsum, wx);
  k_dist<<<512, 256, 0, stream>>>(x, pbig, soft, wsum);
  k_agg<<<1024, 256, 0, stream>>>(x, soft, wx);
  k_nodes<<<dim3(K_, B_), 128, 0, stream>>>(wx, wsum, anchor, invsig, out0,
                                            gsum);
  k_final<<<512, 256, 0, stream>>>(out0, gsum);
}